// Round 11
// baseline (79.921 us; speedup 1.0000x reference)
//
#include <hip/hip_runtime.h>
#include <hip/hip_bf16.h>

// Hedgehog linear attention, B=1, L=1024, D=1024, H=16, HD=64, FD=64.
// Round 11: tail fused into ONE kernel via device-scope flag handshakes
// (split-k-style last-block pattern; all 256 blocks co-resident, DAG deps).
// 3 launches.
//  1) prep: W^T bf16 (x4), x bf16, Kq/Kk^T bf16, zero flags
//  2) qkv_feat: GEMM tile 128x64 + fused featmap epilogue (qf/kf/kfT/VT)
//  3) tail_fused per (h,c):
//       p1: Sc bf16 = V^T @ kf, ksum f32 -> publish flags[h,c]
//       p2: spin flags[h,c'<c] -> SP (LDS, f32 accum) + kpL
//       p3: Y = ((QK^T masked)V + Qf SP^T)/z -> publish flagsY[c]
//       p4: spin flagsY[c]==16 -> out tile = Y @ Wo

#define NH 16
#define NC 16

using short8 = __attribute__((ext_vector_type(8))) short;
using f32x4  = __attribute__((ext_vector_type(4))) float;
typedef const __attribute__((address_space(1))) char* gptr1;
typedef __attribute__((address_space(3))) char* lptr3;

static __device__ __forceinline__ unsigned short bf16bits(float x) {
    __hip_bfloat16 h = __float2bfloat16(x);
    return __builtin_bit_cast(unsigned short, h);
}
static __device__ __forceinline__ float b2f(unsigned short u) {
    return __builtin_bit_cast(float, (unsigned int)u << 16);
}
#define SWZ(row, cb) ((cb) ^ (((row) & 7) << 4))

template<int RS>
static __device__ __forceinline__ short8 ldfrag(const char* buf, int row, int kelem) {
    return *(const short8*)(buf + row * RS + SWZ(row, kelem * 2));
}

// ---- prep: z<4 weight transpose+convert; z==4 x convert; z==5 kmat + flag zeroing
__global__ __launch_bounds__(256) void prep(const float* __restrict__ x,
                                            const float* __restrict__ w0,
                                            const float* __restrict__ w1,
                                            const float* __restrict__ w2,
                                            const float* __restrict__ w3,
                                            const float* __restrict__ Kq,
                                            const float* __restrict__ Kk,
                                            __hip_bfloat16* __restrict__ xb,
                                            __hip_bfloat16* __restrict__ d0,
                                            __hip_bfloat16* __restrict__ d1,
                                            __hip_bfloat16* __restrict__ d2,
                                            __hip_bfloat16* __restrict__ d3,
                                            __hip_bfloat16* __restrict__ KqT,
                                            __hip_bfloat16* __restrict__ KkT,
                                            int* __restrict__ flags) {
    const int z = blockIdx.z;
    const int tid = threadIdx.x;
    if (z < 4) {
        const float* src = (z == 0) ? w0 : (z == 1) ? w1 : (z == 2) ? w2 : w3;
        __hip_bfloat16* dst = (z == 0) ? d0 : (z == 1) ? d1 : (z == 2) ? d2 : d3;
        __shared__ float tile[64][68];
        const int bx = blockIdx.x * 64, by = blockIdx.y * 64;
#pragma unroll
        for (int j = 0; j < 4; j++) {
            const int idx = j * 256 + tid;
            const int kr = idx >> 4, c4 = idx & 15;
            float4 v = *(const float4*)&src[(size_t)(by + kr) * 1024 + bx + c4 * 4];
            *(float4*)&tile[kr][c4 * 4] = v;
        }
        __syncthreads();
        const int n = tid >> 2, k0 = (tid & 3) * 16;
        unsigned short* drow = (unsigned short*)dst + (size_t)(bx + n) * 1024 + by + k0;
#pragma unroll
        for (int q = 0; q < 4; q++) {
            ushort4 o;
            o.x = bf16bits(tile[k0 + q * 4 + 0][n]);
            o.y = bf16bits(tile[k0 + q * 4 + 1][n]);
            o.z = bf16bits(tile[k0 + q * 4 + 2][n]);
            o.w = bf16bits(tile[k0 + q * 4 + 3][n]);
            *(ushort4*)(drow + q * 4) = o;
        }
    } else if (z == 4) {
        const int blk = blockIdx.y * 16 + blockIdx.x;
#pragma unroll
        for (int j = 0; j < 4; j++) {
            const int i = blk * 4096 + j * 1024 + tid * 4;
            float4 v = *(const float4*)(x + i);
            ushort4 o;
            o.x = bf16bits(v.x); o.y = bf16bits(v.y); o.z = bf16bits(v.z); o.w = bf16bits(v.w);
            *(ushort4*)((unsigned short*)xb + i) = o;
        }
    } else {
        const int flat = blockIdx.y * 16 + blockIdx.x;
        if (flat == 32) {
            flags[tid] = 0;          // 256 phase-1 flags
            if (tid < 16) flags[256 + tid] = 0;   // 16 flagsY counters
            return;
        }
        if (flat > 32) return;
        if (flat >= 32) return;
        const int h = flat & 15;
        const float* S = (flat >> 4) ? Kk : Kq;
        __hip_bfloat16* D = (flat >> 4) ? KkT : KqT;
        __shared__ float t[64][65];
#pragma unroll
        for (int j = 0; j < 16; j++) {
            int e = tid + j * 256, r = e >> 6, c = e & 63;
            t[r][c] = S[h * 4096 + r * 64 + c];
        }
        __syncthreads();
#pragma unroll
        for (int j = 0; j < 16; j++) {
            int e = tid + j * 256, r = e >> 6, c = e & 63;
            D[h * 4096 + r * 64 + c] = __float2bfloat16(t[c][r]);
        }
    }
}

// ---- QKV GEMM + fused feature map (validated r5/r10).
__global__ __launch_bounds__(256) void qkv_feat(const __hip_bfloat16* __restrict__ A,
                                                const __hip_bfloat16* __restrict__ B0,
                                                const __hip_bfloat16* __restrict__ B1,
                                                const __hip_bfloat16* __restrict__ B2,
                                                const __hip_bfloat16* __restrict__ KqT,
                                                const __hip_bfloat16* __restrict__ KkT,
                                                __hip_bfloat16* __restrict__ qf,
                                                __hip_bfloat16* __restrict__ kf,
                                                __hip_bfloat16* __restrict__ kfT,
                                                __hip_bfloat16* __restrict__ VT) {
    __shared__ __align__(16) char smem[49152];
    const int tid = threadIdx.x;
    const int bm = blockIdx.y * 128;
    const int which = blockIdx.x >> 4;
    const int h = blockIdx.x & 15;
    const __hip_bfloat16* B = (which == 0) ? B0 : (which == 1) ? B1 : B2;
    const int bn = h * 64;
    const int wid = tid >> 6, lane = tid & 63;
    const int g = lane >> 4, r16 = lane & 15;
    const char* Ab = (const char*)A;
    const char* Bb = (const char*)B;
    f32x4 acc[2][4] = {};

#define QKV_STAGE(dstA, dstB, kbyte)                                                                   \
    do {                                                                                               \
        _Pragma("unroll") for (int it = 0; it < 4; it++) {                                             \
            const int off = it * 4096 + tid * 16;                                                      \
            const int row = off >> 7, cb = off & 127;                                                  \
            __builtin_amdgcn_global_load_lds((gptr1)(Ab + (size_t)(bm + row) * 2048 + (kbyte) + SWZ(row, cb)), \
                                             (lptr3)((dstA) + it * 4096 + wid * 1024), 16, 0, 0);      \
        }                                                                                              \
        _Pragma("unroll") for (int it = 0; it < 2; it++) {                                             \
            const int off = it * 4096 + tid * 16;                                                      \
            const int row = off >> 7, cb = off & 127;                                                  \
            __builtin_amdgcn_global_load_lds((gptr1)(Bb + (size_t)(bn + row) * 2048 + (kbyte) + SWZ(row, cb)), \
                                             (lptr3)((dstB) + it * 4096 + wid * 1024), 16, 0, 0);      \
        }                                                                                              \
    } while (0)

    QKV_STAGE(smem, smem + 32768, 0);
    for (int kt = 0; kt < 16; kt++) {
        char* Ac = smem + ((kt & 1) ? 16384 : 0);
        char* Bc = smem + 32768 + ((kt & 1) ? 8192 : 0);
        if (kt < 15) {
            char* An = smem + ((kt & 1) ? 0 : 16384);
            char* Bn = smem + 32768 + ((kt & 1) ? 0 : 8192);
            QKV_STAGE(An, Bn, (kt + 1) * 128);
            asm volatile("s_waitcnt vmcnt(6)" ::: "memory");
        } else {
            asm volatile("s_waitcnt vmcnt(0)" ::: "memory");
        }
        __builtin_amdgcn_s_barrier();
#pragma unroll
        for (int ks = 0; ks < 2; ks++) {
            short8 af[2], bfr[4];
#pragma unroll
            for (int m = 0; m < 2; m++)
                af[m] = ldfrag<128>(Ac, wid * 32 + m * 16 + r16, ks * 32 + g * 8);
#pragma unroll
            for (int n = 0; n < 4; n++)
                bfr[n] = ldfrag<128>(Bc, n * 16 + r16, ks * 32 + g * 8);
#pragma unroll
            for (int m = 0; m < 2; m++)
#pragma unroll
                for (int n = 0; n < 4; n++)
                    acc[m][n] = __builtin_amdgcn_mfma_f32_16x16x32_bf16(af[m], bfr[n], acc[m][n], 0, 0, 0);
        }
        asm volatile("s_waitcnt lgkmcnt(0)" ::: "memory");
        __builtin_amdgcn_s_barrier();
    }
#undef QKV_STAGE

    if (which == 2) {
#pragma unroll
        for (int m = 0; m < 2; m++)
#pragma unroll
            for (int n = 0; n < 4; n++) {
                const int col = bn + n * 16 + r16;
                const int row0 = bm + wid * 32 + m * 16 + g * 4;
                ushort4 v;
                v.x = bf16bits(acc[m][n][0]); v.y = bf16bits(acc[m][n][1]);
                v.z = bf16bits(acc[m][n][2]); v.w = bf16bits(acc[m][n][3]);
                *(ushort4*)((unsigned short*)VT + (size_t)col * 1024 + row0) = v;
            }
        return;
    }

    const bool kside = (which == 1);
    char* XS = smem + 32768;
#pragma unroll
    for (int m = 0; m < 2; m++)
#pragma unroll
        for (int n = 0; n < 4; n++)
#pragma unroll
            for (int i = 0; i < 4; i++) {
                const int row = wid * 32 + m * 16 + g * 4 + i;
                *(unsigned short*)(XS + row * 128 + SWZ(row, (n * 16 + r16) * 2)) = bf16bits(acc[m][n][i]);
            }
    {
        const char* KTp = (const char*)(kside ? KkT : KqT);
#pragma unroll
        for (int it = 0; it < 2; it++) {
            const int off = it * 4096 + tid * 16;
            const int row = off >> 7, cb = off & 127;
            __builtin_amdgcn_global_load_lds((gptr1)(KTp + (size_t)(h * 64 + row) * 128 + SWZ(row, cb)),
                                             (lptr3)(smem + it * 4096 + wid * 1024), 16, 0, 0);
        }
    }
    __syncthreads();

    f32x4 fr[2][4] = {};
#pragma unroll
    for (int ks = 0; ks < 2; ks++) {
        short8 af[2], bfr[4];
#pragma unroll
        for (int m = 0; m < 2; m++)
            af[m] = ldfrag<128>(XS, wid * 32 + m * 16 + r16, ks * 32 + g * 8);
#pragma unroll
        for (int n = 0; n < 4; n++)
            bfr[n] = ldfrag<128>(smem, n * 16 + r16, ks * 32 + g * 8);
#pragma unroll
        for (int m = 0; m < 2; m++)
#pragma unroll
            for (int n = 0; n < 4; n++)
                fr[m][n] = __builtin_amdgcn_mfma_f32_16x16x32_bf16(af[m], bfr[n], fr[m][n], 0, 0, 0);
    }
    if (kside) __syncthreads();

    char* ft = smem;
    __hip_bfloat16* feat = kside ? kf : qf;
#pragma unroll
    for (int m = 0; m < 2; m++)
#pragma unroll
        for (int i = 0; i < 4; i++) {
            const int row = wid * 32 + m * 16 + g * 4 + i;
            float m1 = fr[m][0][i], m2 = -fr[m][0][i];
#pragma unroll
            for (int n = 1; n < 4; n++) {
                m1 = fmaxf(m1, fr[m][n][i]);
                m2 = fmaxf(m2, -fr[m][n][i]);
            }
#pragma unroll
            for (int off = 8; off; off >>= 1) {
                m1 = fmaxf(m1, __shfl_xor(m1, off));
                m2 = fmaxf(m2, __shfl_xor(m2, off));
            }
            float e1[4], e2[4], s1 = 0.f, s2 = 0.f;
#pragma unroll
            for (int n = 0; n < 4; n++) {
                e1[n] = __expf(fr[m][n][i] - m1);  s1 += e1[n];
                e2[n] = __expf(-fr[m][n][i] - m2); s2 += e2[n];
            }
#pragma unroll
            for (int off = 8; off; off >>= 1) {
                s1 += __shfl_xor(s1, off);
                s2 += __shfl_xor(s2, off);
            }
            const float i1 = 1.f / s1, i2 = 1.f / s2;
            __hip_bfloat16* fo = feat + ((size_t)(h * 1024 + bm + row)) * 128;
#pragma unroll
            for (int n = 0; n < 4; n++) {
                const int col = n * 16 + r16;
                unsigned short v1 = bf16bits(fmaxf(e1[n] * i1, 1e-12f));
                unsigned short v2 = bf16bits(fmaxf(e2[n] * i2, 1e-12f));
                *(unsigned short*)(fo + col) = v1;
                *(unsigned short*)(fo + col + 64) = v2;
                if (kside) {
                    *(unsigned short*)(ft + col * 256 + SWZ(col, row * 2)) = v1;
                    *(unsigned short*)(ft + (col + 64) * 256 + SWZ(col + 64, row * 2)) = v2;
                }
            }
        }
    if (kside) {
        __syncthreads();
#pragma unroll
        for (int j = 0; j < 8; j++) {
            const int off = (tid + j * 256) * 16;
            const int row = off >> 8, cb = off & 255;
            short8 v = *(const short8*)(ft + row * 256 + SWZ(row, cb));
            *(short8*)((char*)kfT + ((size_t)(h * 128 + row) * 1024 + bm) * 2 + cb) = v;
        }
    }
}

// ---- fused tail: chunk_sums -> (flag sync) -> SP/kp in LDS -> chunk_out -> (flag sync) -> final GEMM
__global__ __launch_bounds__(256) void tail_fused(const __hip_bfloat16* __restrict__ kfT,
                                                  const __hip_bfloat16* __restrict__ VT,
                                                  const __hip_bfloat16* __restrict__ qf,
                                                  const __hip_bfloat16* __restrict__ kf,
                                                  __hip_bfloat16* __restrict__ Scb,
                                                  float* __restrict__ ksum,
                                                  int* __restrict__ flags,
                                                  __hip_bfloat16* __restrict__ Y,
                                                  const __hip_bfloat16* __restrict__ Wot,
                                                  float* __restrict__ out) {
    __shared__ __align__(16) char smem[65536];
    char* QF  = smem;             // 16KB
    char* KF  = smem + 16384;     // 16KB (phase1 KTs; phase4 Bbuf)
    char* SP  = smem + 32768;     // 16KB
    char* VTs = smem + 49152;     // 8KB
    char* AM  = smem + 57344;     // 8KB
    __shared__ float kpL[128];
    __shared__ float zi[64], invz[64];
    const int h = blockIdx.y, c = blockIdx.x, l0 = c * 64;
    const int tid = threadIdx.x, lane = tid & 63, wid = tid >> 6;
    const int r16 = lane & 15, g = lane >> 4;
    int* flagsY = flags + 256;

    // ===== phase 1: Sc[h][c] bf16 = V^T @ kf, ksum f32 (validated chunk_sums) =====
    {
#pragma unroll
        for (int it = 0; it < 2; it++) {
            const int off = it * 4096 + tid * 16;
            const int row = off >> 7, cb = off & 127;
            __builtin_amdgcn_global_load_lds((gptr1)((const char*)VT + ((size_t)(h * 64 + row) * 1024 + l0) * 2 + SWZ(row, cb)),
                                             (lptr3)(VTs + it * 4096 + wid * 1024), 16, 0, 0);
        }
#pragma unroll
        for (int it = 0; it < 4; it++) {
            const int off = it * 4096 + tid * 16;
            const int row = off >> 7, cb = off & 127;
            __builtin_amdgcn_global_load_lds((gptr1)((const char*)kfT + ((size_t)(h * 128 + row) * 1024 + l0) * 2 + SWZ(row, cb)),
                                             (lptr3)(KF + it * 4096 + wid * 1024), 16, 0, 0);
        }
        __syncthreads();
        f32x4 acc[8] = {};
#pragma unroll
        for (int ks = 0; ks < 2; ks++) {
            short8 a = ldfrag<128>(VTs, wid * 16 + r16, ks * 32 + g * 8);
#pragma unroll
            for (int n = 0; n < 8; n++) {
                short8 bb = ldfrag<128>(KF, n * 16 + r16, ks * 32 + g * 8);
                acc[n] = __builtin_amdgcn_mfma_f32_16x16x32_bf16(a, bb, acc[n], 0, 0, 0);
            }
        }
        unsigned short* o = (unsigned short*)Scb + (size_t)(h * NC + c) * 8192;
#pragma unroll
        for (int n = 0; n < 8; n++)
#pragma unroll
            for (int i = 0; i < 4; i++)
                o[(wid * 16 + g * 4 + i) * 128 + n * 16 + r16] = bf16bits(acc[n][i]);
        if (tid < 128) {
            float s = 0.f;
#pragma unroll 8
            for (int t = 0; t < 64; t++)
                s += b2f(*(const unsigned short*)(KF + tid * 128 + SWZ(tid, t * 2)));
            ksum[(size_t)(h * NC + c) * 128 + tid] = s;
        }
    }
    __syncthreads();   // all Sc/ksum stores drained (vmcnt(0) before barrier)
    if (tid == 0)
        __hip_atomic_store(&flags[h * NC + c], 1, __ATOMIC_RELEASE, __HIP_MEMORY_SCOPE_AGENT);

    // issue QF/KF staging early (independent of flags; hides latency under spin)
#pragma unroll
    for (int it = 0; it < 4; it++) {
        const int off = it * 4096 + wid * 1024 + lane * 16;
        const int row = off >> 8, cb = off & 255;
        const int sw = SWZ(row, cb);
        __builtin_amdgcn_global_load_lds((gptr1)((const char*)qf + ((size_t)(h * 1024 + l0 + row)) * 256 + sw),
                                         (lptr3)(QF + it * 4096 + wid * 1024), 16, 0, 0);
        __builtin_amdgcn_global_load_lds((gptr1)((const char*)kf + ((size_t)(h * 1024 + l0 + row)) * 256 + sw),
                                         (lptr3)(KF + it * 4096 + wid * 1024), 16, 0, 0);
    }

    // spin: wait for chunks c' < c of this head
    if (tid < c)
        while (__hip_atomic_load(&flags[h * NC + tid], __ATOMIC_ACQUIRE, __HIP_MEMORY_SCOPE_AGENT) == 0) {}
    __syncthreads();

    // ===== phase 2: SP (bf16, swizzled LDS) = sum_{c'<c} Sc[h][c'] (f32 accum); kpL =====
    {
        const int e0 = tid * 32;            // 8192 elems / 256 threads
        const int d = e0 >> 7, f0 = e0 & 127;
        float a[32];
#pragma unroll
        for (int j = 0; j < 32; j++) a[j] = 0.f;
        for (int cp = 0; cp < c; cp++) {
            const unsigned short* p = (const unsigned short*)Scb + (size_t)(h * NC + cp) * 8192 + e0;
#pragma unroll
            for (int q = 0; q < 4; q++) {
                short8 v = *(const short8*)(p + q * 8);
#pragma unroll
                for (int j = 0; j < 8; j++) a[q * 8 + j] += b2f((unsigned short)v[j]);
            }
        }
#pragma unroll
        for (int q = 0; q < 4; q++) {
            short8 w;
#pragma unroll
            for (int j = 0; j < 8; j++) w[j] = (short)bf16bits(a[q * 8 + j]);
            *(short8*)(SP + d * 256 + SWZ(d, (f0 + q * 8) * 2)) = w;
        }
        if (tid < 128) {
            float s = 0.f;
            for (int cp = 0; cp < c; cp++)
                s += ksum[(size_t)(h * NC + cp) * 128 + tid];
            kpL[tid] = s;
        }
    }
    __syncthreads();   // QF/KF staged, SP/kpL written

    // ===== phase 3: Y = ((Qf Kf^T masked) V + Qf SP^T) / z (validated chunk_out) =====
    {
        f32x4 a4[4] = {};
#pragma unroll
        for (int ks = 0; ks < 4; ks++) {
            short8 a = ldfrag<256>(QF, wid * 16 + r16, ks * 32 + g * 8);
#pragma unroll
            for (int n = 0; n < 4; n++) {
                short8 bb = ldfrag<256>(KF, n * 16 + r16, ks * 32 + g * 8);
                a4[n] = __builtin_amdgcn_mfma_f32_16x16x32_bf16(a, bb, a4[n], 0, 0, 0);
            }
        }
        const int rowl = wid * 16 + g * 4;
#pragma unroll
        for (int i = 0; i < 4; i++) {
            float r = 0.f;
#pragma unroll
            for (int n = 0; n < 4; n++) {
                const int col = n * 16 + r16;
                float v = (col <= rowl + i) ? a4[n][i] : 0.f;
                a4[n][i] = v;
                r += v;
            }
#pragma unroll
            for (int off = 8; off; off >>= 1) r += __shfl_xor(r, off);
            if (r16 == 0) zi[rowl + i] = r;
#pragma unroll
            for (int n = 0; n < 4; n++)
                *(unsigned short*)(AM + (rowl + i) * 128 + SWZ(rowl + i, (n * 16 + r16) * 2)) = bf16bits(a4[n][i]);
        }
        __syncthreads();

        if (tid < 64) {
            float z = zi[tid] + 1e-12f;
#pragma unroll 8
            for (int f = 0; f < 128; f++)
                z += b2f(*(const unsigned short*)(QF + tid * 256 + SWZ(tid, f * 2))) * kpL[f];
            invz[tid] = 1.f / z;
        }

        f32x4 o4[4] = {};
#pragma unroll
        for (int ks = 0; ks < 2; ks++) {
            short8 a = ldfrag<128>(AM, wid * 16 + r16, ks * 32 + g * 8);
#pragma unroll
            for (int n = 0; n < 4; n++) {
                short8 bb = ldfrag<128>(VTs, n * 16 + r16, ks * 32 + g * 8);
                o4[n] = __builtin_amdgcn_mfma_f32_16x16x32_bf16(a, bb, o4[n], 0, 0, 0);
            }
        }
#pragma unroll
        for (int ks = 0; ks < 4; ks++) {
            short8 a = ldfrag<256>(QF, wid * 16 + r16, ks * 32 + g * 8);
#pragma unroll
            for (int n = 0; n < 4; n++) {
                short8 bb = ldfrag<256>(SP, n * 16 + r16, ks * 32 + g * 8);
                o4[n] = __builtin_amdgcn_mfma_f32_16x16x32_bf16(a, bb, o4[n], 0, 0, 0);
            }
        }
        __syncthreads();   // invz visible to all waves (R10 lesson)
#pragma unroll
        for (int n = 0; n < 4; n++)
#pragma unroll
            for (int i = 0; i < 4; i++) {
                const int row = rowl + i, col = n * 16 + r16;
                Y[((size_t)(l0 + row)) * 1024 + h * 64 + col] = __float2bfloat16(o4[n][i] * invz[row]);
            }
    }
    __syncthreads();   // Y stores drained
    if (tid == 0) {
        __hip_atomic_fetch_add(&flagsY[c], 1, __ATOMIC_RELEASE, __HIP_MEMORY_SCOPE_AGENT);
        while (__hip_atomic_load(&flagsY[c], __ATOMIC_ACQUIRE, __HIP_MEMORY_SCOPE_AGENT) < NH) {}
    }
    __syncthreads();

    // ===== phase 4: out tile (bm=c*64, bn=h*64) = Y @ Wo (validated gemm_final) =====
    {
        const int bm = c * 64, bn = h * 64;
        const int wr = wid >> 1, wc = wid & 1;
        const char* Ab = (const char*)Y;
        const char* Bb = (const char*)Wot;
        f32x4 acc[2][2] = {};

#define FIN_STAGE(dstA, dstB, kbyte)                                                                   \
    do {                                                                                               \
        _Pragma("unroll") for (int it = 0; it < 2; it++) {                                             \
            const int off = it * 4096 + tid * 16;                                                      \
            const int row = off >> 7, cb = off & 127;                                                  \
            __builtin_amdgcn_global_load_lds((gptr1)(Ab + (size_t)(bm + row) * 2048 + (kbyte) + SWZ(row, cb)), \
                                             (lptr3)((dstA) + it * 4096 + wid * 1024), 16, 0, 0);      \
            __builtin_amdgcn_global_load_lds((gptr1)(Bb + (size_t)(bn + row) * 2048 + (kbyte) + SWZ(row, cb)), \
                                             (lptr3)((dstB) + it * 4096 + wid * 1024), 16, 0, 0);      \
        }                                                                                              \
    } while (0)

        FIN_STAGE(QF, KF, 0);
        for (int kt = 0; kt < 16; kt++) {
            char* Ac = QF + ((kt & 1) ? 8192 : 0);
            char* Bc = KF + ((kt & 1) ? 8192 : 0);
            if (kt < 15) {
                char* An = QF + ((kt & 1) ? 0 : 8192);
                char* Bn = KF + ((kt & 1) ? 0 : 8192);
                FIN_STAGE(An, Bn, (kt + 1) * 128);
                asm volatile("s_waitcnt vmcnt(4)" ::: "memory");
            } else {
                asm volatile("s_waitcnt vmcnt(0)" ::: "memory");
            }
            __builtin_amdgcn_s_barrier();
#pragma unroll
            for (int ks = 0; ks < 2; ks++) {
                short8 af[2], bfr[2];
#pragma unroll
                for (int m = 0; m < 2; m++)
                    af[m] = ldfrag<128>(Ac, wr * 32 + m * 16 + r16, ks * 32 + g * 8);
#pragma unroll
                for (int n = 0; n < 2; n++)
                    bfr[n] = ldfrag<128>(Bc, wc * 32 + n * 16 + r16, ks * 32 + g * 8);
#pragma unroll
                for (int m = 0; m < 2; m++)
#pragma unroll
                    for (int n = 0; n < 2; n++)
                        acc[m][n] = __builtin_amdgcn_mfma_f32_16x16x32_bf16(af[m], bfr[n], acc[m][n], 0, 0, 0);
            }
            asm volatile("s_waitcnt lgkmcnt(0)" ::: "memory");
            __builtin_amdgcn_s_barrier();
        }
#undef FIN_STAGE
#pragma unroll
        for (int m = 0; m < 2; m++)
#pragma unroll
            for (int n = 0; n < 2; n++)
#pragma unroll
                for (int i = 0; i < 4; i++) {
                    const int row = bm + wr * 32 + m * 16 + g * 4 + i;
                    const int col = bn + wc * 32 + n * 16 + r16;
                    out[(size_t)row * 1024 + col] = acc[m][n][i];
                }
    }
}

extern "C" void kernel_launch(void* const* d_in, const int* in_sizes, int n_in,
                              void* d_out, int out_size, void* d_ws, size_t ws_size,
                              hipStream_t stream) {
    const float* x  = (const float*)d_in[0];
    const float* Wq = (const float*)d_in[1];
    const float* Wk = (const float*)d_in[2];
    const float* Wv = (const float*)d_in[3];
    const float* Wo = (const float*)d_in[4];
    const float* Kq = (const float*)d_in[5];
    const float* Kk = (const float*)d_in[6];
    float* out = (float*)d_out;
    float* ws = (float*)d_ws;

    const size_t M1 = 1024 * 1024;
    if (ws_size < 10 * M1 * sizeof(float)) return;

    __hip_bfloat16* xb  = (__hip_bfloat16*)(ws);
    __hip_bfloat16* Wqt = (__hip_bfloat16*)(ws + M1 / 2);
    __hip_bfloat16* Wkt = (__hip_bfloat16*)(ws + 1 * M1);
    __hip_bfloat16* Wvt = (__hip_bfloat16*)(ws + 3 * M1 / 2);
    __hip_bfloat16* Wot = (__hip_bfloat16*)(ws + 2 * M1);
    __hip_bfloat16* KqT = (__hip_bfloat16*)(ws + 5 * M1 / 2);
    __hip_bfloat16* KkT = (__hip_bfloat16*)(ws + 5 * M1 / 2 + 32768);
    __hip_bfloat16* VT  = (__hip_bfloat16*)(ws + 3 * M1);
    __hip_bfloat16* qfb = (__hip_bfloat16*)(ws + 7 * M1 / 2);
    __hip_bfloat16* kfb = (__hip_bfloat16*)(ws + 9 * M1 / 2);
    __hip_bfloat16* kfT = (__hip_bfloat16*)(ws + 11 * M1 / 2);
    __hip_bfloat16* Scb = (__hip_bfloat16*)(ws + 13 * M1 / 2);
    __hip_bfloat16* Yb  = (__hip_bfloat16*)(ws + 15 * M1 / 2);
    float* ksum = ws + 9 * M1;                       // 32768 floats
    int*   flags = (int*)(ws + 9 * M1 + 32768);      // 256 + 16 ints

    prep<<<dim3(16, 16, 6), 256, 0, stream>>>(x, Wq, Wk, Wv, Wo, Kq, Kk,
                                              xb, Wqt, Wkt, Wvt, Wot, KqT, KkT, flags);
    qkv_feat<<<dim3(48, 8), 256, 0, stream>>>(xb, Wqt, Wkt, Wvt, KqT, KkT, qfb, kfb, kfT, VT);
    tail_fused<<<dim3(NC, NH), 256, 0, stream>>>(kfT, VT, qfb, kfb, Scb, ksum, flags, Yb, Wot, out);
}

// Round 12
// 64.613 us; speedup vs baseline: 1.2369x; 1.2369x over previous
//
#include <hip/hip_runtime.h>
#include <hip/hip_bf16.h>

// Hedgehog linear attention, B=1, L=1024, D=1024, H=16, HD=64, FD=64.
// Round 12: R10 with chunk_sums+prefix_scan replaced by chunk_scan (R8's
// serial-walk kernel, exonerated by R10's root-cause: the R8/R9 failures were
// chunk_out's missing invz barrier, fixed in R10). 5 launches.
//  1) prep: W^T bf16 (x4), x bf16, Kq/Kk^T bf16
//  2) qkv_feat: GEMM tile 128x64 + fused featmap epilogue (qf/kf/kfT/VT)
//  3) chunk_scan: Sp bf16 (f32 MFMA accum) + kp f32, serial chunk walk
//  4) chunk_out_mfma: Y bf16 (WITH invz barrier)
//  5) gemm_final: out f32 = Y @ Wo

#define NH 16
#define NC 16

using short8 = __attribute__((ext_vector_type(8))) short;
using f32x4  = __attribute__((ext_vector_type(4))) float;
typedef const __attribute__((address_space(1))) char* gptr1;
typedef __attribute__((address_space(3))) char* lptr3;

static __device__ __forceinline__ unsigned short bf16bits(float x) {
    __hip_bfloat16 h = __float2bfloat16(x);
    return __builtin_bit_cast(unsigned short, h);
}
static __device__ __forceinline__ float b2f(unsigned short u) {
    return __builtin_bit_cast(float, (unsigned int)u << 16);
}
#define SWZ(row, cb) ((cb) ^ (((row) & 7) << 4))

template<int RS>
static __device__ __forceinline__ short8 ldfrag(const char* buf, int row, int kelem) {
    return *(const short8*)(buf + row * RS + SWZ(row, kelem * 2));
}

// ---- prep: z<4 weight transpose+convert (64x64 tiles, float4); z==4 x convert; z==5 kmat
__global__ __launch_bounds__(256) void prep(const float* __restrict__ x,
                                            const float* __restrict__ w0,
                                            const float* __restrict__ w1,
                                            const float* __restrict__ w2,
                                            const float* __restrict__ w3,
                                            const float* __restrict__ Kq,
                                            const float* __restrict__ Kk,
                                            __hip_bfloat16* __restrict__ xb,
                                            __hip_bfloat16* __restrict__ d0,
                                            __hip_bfloat16* __restrict__ d1,
                                            __hip_bfloat16* __restrict__ d2,
                                            __hip_bfloat16* __restrict__ d3,
                                            __hip_bfloat16* __restrict__ KqT,
                                            __hip_bfloat16* __restrict__ KkT) {
    const int z = blockIdx.z;
    const int tid = threadIdx.x;
    if (z < 4) {
        const float* src = (z == 0) ? w0 : (z == 1) ? w1 : (z == 2) ? w2 : w3;
        __hip_bfloat16* dst = (z == 0) ? d0 : (z == 1) ? d1 : (z == 2) ? d2 : d3;
        __shared__ float tile[64][68];
        const int bx = blockIdx.x * 64, by = blockIdx.y * 64;
#pragma unroll
        for (int j = 0; j < 4; j++) {
            const int idx = j * 256 + tid;
            const int kr = idx >> 4, c4 = idx & 15;
            float4 v = *(const float4*)&src[(size_t)(by + kr) * 1024 + bx + c4 * 4];
            *(float4*)&tile[kr][c4 * 4] = v;
        }
        __syncthreads();
        const int n = tid >> 2, k0 = (tid & 3) * 16;
        unsigned short* drow = (unsigned short*)dst + (size_t)(bx + n) * 1024 + by + k0;
#pragma unroll
        for (int q = 0; q < 4; q++) {
            ushort4 o;
            o.x = bf16bits(tile[k0 + q * 4 + 0][n]);
            o.y = bf16bits(tile[k0 + q * 4 + 1][n]);
            o.z = bf16bits(tile[k0 + q * 4 + 2][n]);
            o.w = bf16bits(tile[k0 + q * 4 + 3][n]);
            *(ushort4*)(drow + q * 4) = o;
        }
    } else if (z == 4) {
        const int blk = blockIdx.y * 16 + blockIdx.x;
#pragma unroll
        for (int j = 0; j < 4; j++) {
            const int i = blk * 4096 + j * 1024 + tid * 4;
            float4 v = *(const float4*)(x + i);
            ushort4 o;
            o.x = bf16bits(v.x); o.y = bf16bits(v.y); o.z = bf16bits(v.z); o.w = bf16bits(v.w);
            *(ushort4*)((unsigned short*)xb + i) = o;
        }
    } else {
        const int flat = blockIdx.y * 16 + blockIdx.x;
        if (flat >= 32) return;
        const int h = flat & 15;
        const float* S = (flat >> 4) ? Kk : Kq;
        __hip_bfloat16* D = (flat >> 4) ? KkT : KqT;
        __shared__ float t[64][65];
#pragma unroll
        for (int j = 0; j < 16; j++) {
            int e = tid + j * 256, r = e >> 6, c = e & 63;
            t[r][c] = S[h * 4096 + r * 64 + c];
        }
        __syncthreads();
#pragma unroll
        for (int j = 0; j < 16; j++) {
            int e = tid + j * 256, r = e >> 6, c = e & 63;
            D[h * 4096 + r * 64 + c] = __float2bfloat16(t[c][r]);
        }
    }
}

// ---- QKV GEMM + fused feature map (validated r5/r10).
__global__ __launch_bounds__(256) void qkv_feat(const __hip_bfloat16* __restrict__ A,
                                                const __hip_bfloat16* __restrict__ B0,
                                                const __hip_bfloat16* __restrict__ B1,
                                                const __hip_bfloat16* __restrict__ B2,
                                                const __hip_bfloat16* __restrict__ KqT,
                                                const __hip_bfloat16* __restrict__ KkT,
                                                __hip_bfloat16* __restrict__ qf,
                                                __hip_bfloat16* __restrict__ kf,
                                                __hip_bfloat16* __restrict__ kfT,
                                                __hip_bfloat16* __restrict__ VT) {
    __shared__ __align__(16) char smem[49152];
    const int tid = threadIdx.x;
    const int bm = blockIdx.y * 128;
    const int which = blockIdx.x >> 4;
    const int h = blockIdx.x & 15;
    const __hip_bfloat16* B = (which == 0) ? B0 : (which == 1) ? B1 : B2;
    const int bn = h * 64;
    const int wid = tid >> 6, lane = tid & 63;
    const int g = lane >> 4, r16 = lane & 15;
    const char* Ab = (const char*)A;
    const char* Bb = (const char*)B;
    f32x4 acc[2][4] = {};

#define QKV_STAGE(dstA, dstB, kbyte)                                                                   \
    do {                                                                                               \
        _Pragma("unroll") for (int it = 0; it < 4; it++) {                                             \
            const int off = it * 4096 + tid * 16;                                                      \
            const int row = off >> 7, cb = off & 127;                                                  \
            __builtin_amdgcn_global_load_lds((gptr1)(Ab + (size_t)(bm + row) * 2048 + (kbyte) + SWZ(row, cb)), \
                                             (lptr3)((dstA) + it * 4096 + wid * 1024), 16, 0, 0);      \
        }                                                                                              \
        _Pragma("unroll") for (int it = 0; it < 2; it++) {                                             \
            const int off = it * 4096 + tid * 16;                                                      \
            const int row = off >> 7, cb = off & 127;                                                  \
            __builtin_amdgcn_global_load_lds((gptr1)(Bb + (size_t)(bn + row) * 2048 + (kbyte) + SWZ(row, cb)), \
                                             (lptr3)((dstB) + it * 4096 + wid * 1024), 16, 0, 0);      \
        }                                                                                              \
    } while (0)

    QKV_STAGE(smem, smem + 32768, 0);
    for (int kt = 0; kt < 16; kt++) {
        char* Ac = smem + ((kt & 1) ? 16384 : 0);
        char* Bc = smem + 32768 + ((kt & 1) ? 8192 : 0);
        if (kt < 15) {
            char* An = smem + ((kt & 1) ? 0 : 16384);
            char* Bn = smem + 32768 + ((kt & 1) ? 0 : 8192);
            QKV_STAGE(An, Bn, (kt + 1) * 128);
            asm volatile("s_waitcnt vmcnt(6)" ::: "memory");
        } else {
            asm volatile("s_waitcnt vmcnt(0)" ::: "memory");
        }
        __builtin_amdgcn_s_barrier();
#pragma unroll
        for (int ks = 0; ks < 2; ks++) {
            short8 af[2], bfr[4];
#pragma unroll
            for (int m = 0; m < 2; m++)
                af[m] = ldfrag<128>(Ac, wid * 32 + m * 16 + r16, ks * 32 + g * 8);
#pragma unroll
            for (int n = 0; n < 4; n++)
                bfr[n] = ldfrag<128>(Bc, n * 16 + r16, ks * 32 + g * 8);
#pragma unroll
            for (int m = 0; m < 2; m++)
#pragma unroll
                for (int n = 0; n < 4; n++)
                    acc[m][n] = __builtin_amdgcn_mfma_f32_16x16x32_bf16(af[m], bfr[n], acc[m][n], 0, 0, 0);
        }
        asm volatile("s_waitcnt lgkmcnt(0)" ::: "memory");
        __builtin_amdgcn_s_barrier();
    }
#undef QKV_STAGE

    if (which == 2) {
#pragma unroll
        for (int m = 0; m < 2; m++)
#pragma unroll
            for (int n = 0; n < 4; n++) {
                const int col = bn + n * 16 + r16;
                const int row0 = bm + wid * 32 + m * 16 + g * 4;
                ushort4 v;
                v.x = bf16bits(acc[m][n][0]); v.y = bf16bits(acc[m][n][1]);
                v.z = bf16bits(acc[m][n][2]); v.w = bf16bits(acc[m][n][3]);
                *(ushort4*)((unsigned short*)VT + (size_t)col * 1024 + row0) = v;
            }
        return;
    }

    const bool kside = (which == 1);
    char* XS = smem + 32768;
#pragma unroll
    for (int m = 0; m < 2; m++)
#pragma unroll
        for (int n = 0; n < 4; n++)
#pragma unroll
            for (int i = 0; i < 4; i++) {
                const int row = wid * 32 + m * 16 + g * 4 + i;
                *(unsigned short*)(XS + row * 128 + SWZ(row, (n * 16 + r16) * 2)) = bf16bits(acc[m][n][i]);
            }
    {
        const char* KTp = (const char*)(kside ? KkT : KqT);
#pragma unroll
        for (int it = 0; it < 2; it++) {
            const int off = it * 4096 + tid * 16;
            const int row = off >> 7, cb = off & 127;
            __builtin_amdgcn_global_load_lds((gptr1)(KTp + (size_t)(h * 64 + row) * 128 + SWZ(row, cb)),
                                             (lptr3)(smem + it * 4096 + wid * 1024), 16, 0, 0);
        }
    }
    __syncthreads();

    f32x4 fr[2][4] = {};
#pragma unroll
    for (int ks = 0; ks < 2; ks++) {
        short8 af[2], bfr[4];
#pragma unroll
        for (int m = 0; m < 2; m++)
            af[m] = ldfrag<128>(XS, wid * 32 + m * 16 + r16, ks * 32 + g * 8);
#pragma unroll
        for (int n = 0; n < 4; n++)
            bfr[n] = ldfrag<128>(smem, n * 16 + r16, ks * 32 + g * 8);
#pragma unroll
        for (int m = 0; m < 2; m++)
#pragma unroll
            for (int n = 0; n < 4; n++)
                fr[m][n] = __builtin_amdgcn_mfma_f32_16x16x32_bf16(af[m], bfr[n], fr[m][n], 0, 0, 0);
    }
    if (kside) __syncthreads();

    char* ft = smem;
    __hip_bfloat16* feat = kside ? kf : qf;
#pragma unroll
    for (int m = 0; m < 2; m++)
#pragma unroll
        for (int i = 0; i < 4; i++) {
            const int row = wid * 32 + m * 16 + g * 4 + i;
            float m1 = fr[m][0][i], m2 = -fr[m][0][i];
#pragma unroll
            for (int n = 1; n < 4; n++) {
                m1 = fmaxf(m1, fr[m][n][i]);
                m2 = fmaxf(m2, -fr[m][n][i]);
            }
#pragma unroll
            for (int off = 8; off; off >>= 1) {
                m1 = fmaxf(m1, __shfl_xor(m1, off));
                m2 = fmaxf(m2, __shfl_xor(m2, off));
            }
            float e1[4], e2[4], s1 = 0.f, s2 = 0.f;
#pragma unroll
            for (int n = 0; n < 4; n++) {
                e1[n] = __expf(fr[m][n][i] - m1);  s1 += e1[n];
                e2[n] = __expf(-fr[m][n][i] - m2); s2 += e2[n];
            }
#pragma unroll
            for (int off = 8; off; off >>= 1) {
                s1 += __shfl_xor(s1, off);
                s2 += __shfl_xor(s2, off);
            }
            const float i1 = 1.f / s1, i2 = 1.f / s2;
            __hip_bfloat16* fo = feat + ((size_t)(h * 1024 + bm + row)) * 128;
#pragma unroll
            for (int n = 0; n < 4; n++) {
                const int col = n * 16 + r16;
                unsigned short v1 = bf16bits(fmaxf(e1[n] * i1, 1e-12f));
                unsigned short v2 = bf16bits(fmaxf(e2[n] * i2, 1e-12f));
                *(unsigned short*)(fo + col) = v1;
                *(unsigned short*)(fo + col + 64) = v2;
                if (kside) {
                    *(unsigned short*)(ft + col * 256 + SWZ(col, row * 2)) = v1;
                    *(unsigned short*)(ft + (col + 64) * 256 + SWZ(col + 64, row * 2)) = v2;
                }
            }
        }
    if (kside) {
        __syncthreads();
#pragma unroll
        for (int j = 0; j < 8; j++) {
            const int off = (tid + j * 256) * 16;
            const int row = off >> 8, cb = off & 255;
            short8 v = *(const short8*)(ft + row * 256 + SWZ(row, cb));
            *(short8*)((char*)kfT + ((size_t)(h * 128 + row) * 1024 + bm) * 2 + cb) = v;
        }
    }
}

// ---- chunk_scan: per (dh, h) block walks chunks 0..15 once.
// Maintains S[32d][128f] f32 in regs; writes EXCLUSIVE prefix Sp bf16 per chunk;
// dh==0 block also maintains kprun and writes kp f32 per chunk.
__global__ __launch_bounds__(256) void chunk_scan(const __hip_bfloat16* __restrict__ kfT,
                                                  const __hip_bfloat16* __restrict__ VT,
                                                  __hip_bfloat16* __restrict__ Sp,
                                                  float* __restrict__ kp) {
    __shared__ __align__(16) char smem[40960];   // 2 bufs x 20KB: [VT 4KB | kfT 16KB]
    __shared__ float kprun[128];
    __shared__ float kpP[2][128];
    const int h = blockIdx.y, dh = blockIdx.x;   // dh in {0,1}: d rows [dh*32, dh*32+32)
    const int tid = threadIdx.x, lane = tid & 63, wid = tid >> 6;
    const int r16 = lane & 15, g = lane >> 4;
    if (tid < 128) kprun[tid] = 0.f;

    f32x4 acc[2][2] = {};   // [mt][nt]: d = dh*32+mt*16+g*4+i ; f = wid*32+nt*16+r16

#define CS_STAGE(p, kc)                                                                                 \
    do {                                                                                                \
        char* bufp = smem + (p) * 20480;                                                                \
        {                                                                                               \
            const int off = tid * 16;                                                                   \
            const int row = off >> 7, cb = off & 127;                                                   \
            __builtin_amdgcn_global_load_lds((gptr1)((const char*)VT + ((size_t)(h * 64 + dh * 32 + row) * 1024 + (kc) * 64) * 2 + SWZ(row, cb)), \
                                             (lptr3)(bufp + wid * 1024), 16, 0, 0);                     \
        }                                                                                               \
        _Pragma("unroll") for (int it = 0; it < 4; it++) {                                              \
            const int off = it * 4096 + tid * 16;                                                       \
            const int row = off >> 7, cb = off & 127;                                                   \
            __builtin_amdgcn_global_load_lds((gptr1)((const char*)kfT + ((size_t)(h * 128 + row) * 1024 + (kc) * 64) * 2 + SWZ(row, cb)), \
                                             (lptr3)(bufp + 4096 + it * 4096 + wid * 1024), 16, 0, 0);  \
        }                                                                                               \
    } while (0)

    CS_STAGE(0, 0);
    for (int c = 0; c < NC; c++) {
        char* VTc = smem + (c & 1) * 20480;
        char* KTc = VTc + 4096;
        if (c + 1 < NC) {
            CS_STAGE((c + 1) & 1, c + 1);
            asm volatile("s_waitcnt vmcnt(5)" ::: "memory");
        } else {
            asm volatile("s_waitcnt vmcnt(0)" ::: "memory");
        }
        __builtin_amdgcn_s_barrier();   // chunk c staged; kprun current through c-1

        // exclusive prefix: write current S as Sp[h][c] (bf16)
        unsigned short* SpO = (unsigned short*)Sp + (size_t)(h * NC + c) * 8192;
#pragma unroll
        for (int mt = 0; mt < 2; mt++)
#pragma unroll
            for (int nt = 0; nt < 2; nt++)
#pragma unroll
                for (int i = 0; i < 4; i++) {
                    const int d = dh * 32 + mt * 16 + g * 4 + i;
                    const int f = wid * 32 + nt * 16 + r16;
                    SpO[d * 128 + f] = bf16bits(acc[mt][nt][i]);
                }
        if (dh == 0 && tid < 128) kp[(size_t)(h * NC + c) * 128 + tid] = kprun[tid];

        // accumulate chunk c: S += VT_chunk @ kfT_chunk^T
#pragma unroll
        for (int ks = 0; ks < 2; ks++) {
            short8 af[2];
#pragma unroll
            for (int mt = 0; mt < 2; mt++)
                af[mt] = ldfrag<128>(VTc, mt * 16 + r16, ks * 32 + g * 8);
#pragma unroll
            for (int nt = 0; nt < 2; nt++) {
                short8 bb = ldfrag<128>(KTc, wid * 32 + nt * 16 + r16, ks * 32 + g * 8);
#pragma unroll
                for (int mt = 0; mt < 2; mt++)
                    acc[mt][nt] = __builtin_amdgcn_mfma_f32_16x16x32_bf16(af[mt], bb, acc[mt][nt], 0, 0, 0);
            }
        }
        // kp partials: thread (half, f) sums 32 t-values of kfT row f
        {
            const int f = tid & 127, half = tid >> 7;
            float s = 0.f;
#pragma unroll
            for (int j = 0; j < 4; j++) {
                short8 v = ldfrag<128>(KTc, f, half * 32 + j * 8);
#pragma unroll
                for (int e = 0; e < 8; e++) s += b2f((unsigned short)v[e]);
            }
            kpP[half][f] = s;
        }
        asm volatile("s_waitcnt lgkmcnt(0)" ::: "memory");
        __builtin_amdgcn_s_barrier();   // buffer c reads done; kpP ready
        if (tid < 128) kprun[tid] += kpP[0][tid] + kpP[1][tid];
        // next iteration's first barrier orders kprun update before its kp read
    }
#undef CS_STAGE
}

// ---- chunk_out: Y = ((Qf Kf^T masked) V + Qf Sp^T) / z, bf16 out (validated r10)
__global__ __launch_bounds__(256) void chunk_out_mfma(const __hip_bfloat16* __restrict__ qf,
                                                      const __hip_bfloat16* __restrict__ kf,
                                                      const __hip_bfloat16* __restrict__ VT,
                                                      const __hip_bfloat16* __restrict__ Sp,
                                                      const float* __restrict__ kp,
                                                      __hip_bfloat16* __restrict__ Y) {
    const int h = blockIdx.y, c = blockIdx.x, l0 = c * 64;
    __shared__ __align__(16) char QF[64 * 256];
    __shared__ __align__(16) char KF[64 * 256];
    __shared__ __align__(16) char SP[64 * 256];
    __shared__ __align__(16) char VTs[64 * 128];
    __shared__ __align__(16) char AM[64 * 128];
    __shared__ float zi[64];
    __shared__ float invz[64];
    const int tid = threadIdx.x, lane = tid & 63, wid = tid >> 6;
    const int r16 = lane & 15, g = lane >> 4;

#pragma unroll
    for (int it = 0; it < 4; it++) {
        const int off = it * 4096 + wid * 1024 + lane * 16;
        const int row = off >> 8, cb = off & 255;
        const int sw = SWZ(row, cb);
        __builtin_amdgcn_global_load_lds((gptr1)((const char*)qf + ((size_t)(h * 1024 + l0 + row)) * 256 + sw),
                                         (lptr3)(QF + it * 4096 + wid * 1024), 16, 0, 0);
        __builtin_amdgcn_global_load_lds((gptr1)((const char*)kf + ((size_t)(h * 1024 + l0 + row)) * 256 + sw),
                                         (lptr3)(KF + it * 4096 + wid * 1024), 16, 0, 0);
        __builtin_amdgcn_global_load_lds((gptr1)((const char*)Sp + ((size_t)((h * NC + c) * 64 + row)) * 256 + sw),
                                         (lptr3)(SP + it * 4096 + wid * 1024), 16, 0, 0);
    }
#pragma unroll
    for (int it = 0; it < 2; it++) {
        const int off = it * 4096 + wid * 1024 + lane * 16;
        const int row = off >> 7, cb = off & 127;
        __builtin_amdgcn_global_load_lds((gptr1)((const char*)VT + ((size_t)(h * 64 + row) * 1024 + l0) * 2 + SWZ(row, cb)),
                                         (lptr3)(VTs + it * 4096 + wid * 1024), 16, 0, 0);
    }
    __syncthreads();

    f32x4 a4[4] = {};
#pragma unroll
    for (int ks = 0; ks < 4; ks++) {
        short8 a = ldfrag<256>(QF, wid * 16 + r16, ks * 32 + g * 8);
#pragma unroll
        for (int n = 0; n < 4; n++) {
            short8 bb = ldfrag<256>(KF, n * 16 + r16, ks * 32 + g * 8);
            a4[n] = __builtin_amdgcn_mfma_f32_16x16x32_bf16(a, bb, a4[n], 0, 0, 0);
        }
    }
    const int rowl = wid * 16 + g * 4;
#pragma unroll
    for (int i = 0; i < 4; i++) {
        float r = 0.f;
#pragma unroll
        for (int n = 0; n < 4; n++) {
            const int col = n * 16 + r16;
            float v = (col <= rowl + i) ? a4[n][i] : 0.f;
            a4[n][i] = v;
            r += v;
        }
#pragma unroll
        for (int off = 8; off; off >>= 1) r += __shfl_xor(r, off);
        if (r16 == 0) zi[rowl + i] = r;
#pragma unroll
        for (int n = 0; n < 4; n++)
            *(unsigned short*)(AM + (rowl + i) * 128 + SWZ(rowl + i, (n * 16 + r16) * 2)) = bf16bits(a4[n][i]);
    }
    __syncthreads();

    if (tid < 64) {
        float z = zi[tid] + 1e-12f;
        const float* kpp = kp + (size_t)(h * NC + c) * 128;
#pragma unroll 8
        for (int f = 0; f < 128; f++)
            z += b2f(*(const unsigned short*)(QF + tid * 256 + SWZ(tid, f * 2))) * kpp[f];
        invz[tid] = 1.f / z;
    }

    f32x4 o4[4] = {};
#pragma unroll
    for (int ks = 0; ks < 2; ks++) {
        short8 a = ldfrag<128>(AM, wid * 16 + r16, ks * 32 + g * 8);
#pragma unroll
        for (int n = 0; n < 4; n++) {
            short8 bb = ldfrag<128>(VTs, n * 16 + r16, ks * 32 + g * 8);
            o4[n] = __builtin_amdgcn_mfma_f32_16x16x32_bf16(a, bb, o4[n], 0, 0, 0);
        }
    }
#pragma unroll
    for (int ks = 0; ks < 4; ks++) {
        short8 a = ldfrag<256>(QF, wid * 16 + r16, ks * 32 + g * 8);
#pragma unroll
        for (int n = 0; n < 4; n++) {
            short8 bb = ldfrag<256>(SP, n * 16 + r16, ks * 32 + g * 8);
            o4[n] = __builtin_amdgcn_mfma_f32_16x16x32_bf16(a, bb, o4[n], 0, 0, 0);
        }
    }
    __syncthreads();   // invz (written by wave 0) must be visible to all waves
#pragma unroll
    for (int n = 0; n < 4; n++)
#pragma unroll
        for (int i = 0; i < 4; i++) {
            const int row = rowl + i, col = n * 16 + r16;
            Y[((size_t)(l0 + row)) * 1024 + h * 64 + col] = __float2bfloat16(o4[n][i] * invz[row]);
        }
}

// ---- final GEMM: A bf16 (M x K), B^T bf16 (N x K), C f32; 64x64 tiles, 2-phase dbuf
__global__ __launch_bounds__(256) void gemm_final(const __hip_bfloat16* __restrict__ A,
                                                  const __hip_bfloat16* __restrict__ B,
                                                  float* __restrict__ C) {
    __shared__ __align__(16) char smem[32768];
    const int tid = threadIdx.x;
    const int bm = blockIdx.y * 64, bn = blockIdx.x * 64;
    const int wid = tid >> 6, lane = tid & 63;
    const int g = lane >> 4, r16 = lane & 15;
    const int wr = wid >> 1, wc = wid & 1;
    const char* Ab = (const char*)A;
    const char* Bb = (const char*)B;
    f32x4 acc[2][2] = {};

#define FIN_STAGE(dstA, dstB, kbyte)                                                                   \
    do {                                                                                               \
        _Pragma("unroll") for (int it = 0; it < 2; it++) {                                             \
            const int off = it * 4096 + tid * 16;                                                      \
            const int row = off >> 7, cb = off & 127;                                                  \
            __builtin_amdgcn_global_load_lds((gptr1)(Ab + (size_t)(bm + row) * 2048 + (kbyte) + SWZ(row, cb)), \
                                             (lptr3)((dstA) + it * 4096 + wid * 1024), 16, 0, 0);      \
            __builtin_amdgcn_global_load_lds((gptr1)(Bb + (size_t)(bn + row) * 2048 + (kbyte) + SWZ(row, cb)), \
                                             (lptr3)((dstB) + it * 4096 + wid * 1024), 16, 0, 0);      \
        }                                                                                              \
    } while (0)

    FIN_STAGE(smem, smem + 16384, 0);
    for (int kt = 0; kt < 16; kt++) {
        char* Ac = smem + ((kt & 1) ? 8192 : 0);
        char* Bc = smem + 16384 + ((kt & 1) ? 8192 : 0);
        if (kt < 15) {
            char* An = smem + ((kt & 1) ? 0 : 8192);
            char* Bn = smem + 16384 + ((kt & 1) ? 0 : 8192);
            FIN_STAGE(An, Bn, (kt + 1) * 128);
            asm volatile("s_waitcnt vmcnt(4)" ::: "memory");
        } else {
            asm volatile("s_waitcnt vmcnt(0)" ::: "memory");
        }
        __builtin_amdgcn_s_barrier();
#pragma unroll
        for (int ks = 0; ks < 2; ks++) {
            short8 af[2], bfr[2];
#pragma unroll
            for (int m = 0; m < 2; m++)
                af[m] = ldfrag<128>(Ac, wr * 32 + m * 16 + r16, ks * 32 + g * 8);
#pragma unroll
            for (int n = 0; n < 2; n++)
                bfr[n] = ldfrag<128>(Bc, wc * 32 + n * 16 + r16, ks * 32 + g * 8);
#pragma unroll
            for (int m = 0; m < 2; m++)
#pragma unroll
                for (int n = 0; n < 2; n++)
                    acc[m][n] = __builtin_amdgcn_mfma_f32_16x16x32_bf16(af[m], bfr[n], acc[m][n], 0, 0, 0);
        }
        asm volatile("s_waitcnt lgkmcnt(0)" ::: "memory");
        __builtin_amdgcn_s_barrier();
    }
#undef FIN_STAGE
#pragma unroll
    for (int m = 0; m < 2; m++)
#pragma unroll
        for (int n = 0; n < 2; n++)
#pragma unroll
            for (int i = 0; i < 4; i++) {
                const int row = bm + wr * 32 + m * 16 + g * 4 + i;
                const int col = bn + wc * 32 + n * 16 + r16;
                C[(size_t)row * 1024 + col] = acc[m][n][i];
            }
}

extern "C" void kernel_launch(void* const* d_in, const int* in_sizes, int n_in,
                              void* d_out, int out_size, void* d_ws, size_t ws_size,
                              hipStream_t stream) {
    const float* x  = (const float*)d_in[0];
    const float* Wq = (const float*)d_in[1];
    const float* Wk = (const float*)d_in[2];
    const float* Wv = (const float*)d_in[3];
    const float* Wo = (const float*)d_in[4];
    const float* Kq = (const float*)d_in[5];
    const float* Kk = (const float*)d_in[6];
    float* out = (float*)d_out;
    float* ws = (float*)d_ws;

    const size_t M1 = 1024 * 1024;
    if (ws_size < 10 * M1 * sizeof(float)) return;

    __hip_bfloat16* xb  = (__hip_bfloat16*)(ws);
    __hip_bfloat16* Wqt = (__hip_bfloat16*)(ws + M1 / 2);
    __hip_bfloat16* Wkt = (__hip_bfloat16*)(ws + 1 * M1);
    __hip_bfloat16* Wvt = (__hip_bfloat16*)(ws + 3 * M1 / 2);
    __hip_bfloat16* Wot = (__hip_bfloat16*)(ws + 2 * M1);
    __hip_bfloat16* KqT = (__hip_bfloat16*)(ws + 5 * M1 / 2);
    __hip_bfloat16* KkT = (__hip_bfloat16*)(ws + 5 * M1 / 2 + 32768);
    __hip_bfloat16* VT  = (__hip_bfloat16*)(ws + 3 * M1);
    __hip_bfloat16* qfb = (__hip_bfloat16*)(ws + 7 * M1 / 2);
    __hip_bfloat16* kfb = (__hip_bfloat16*)(ws + 9 * M1 / 2);
    __hip_bfloat16* kfT = (__hip_bfloat16*)(ws + 11 * M1 / 2);
    __hip_bfloat16* Spb = (__hip_bfloat16*)(ws + 13 * M1 / 2);
    __hip_bfloat16* Yb  = (__hip_bfloat16*)(ws + 15 * M1 / 2);
    float* kp = ws + 9 * M1;

    prep<<<dim3(16, 16, 6), 256, 0, stream>>>(x, Wq, Wk, Wv, Wo, Kq, Kk,
                                              xb, Wqt, Wkt, Wvt, Wot, KqT, KkT);
    qkv_feat<<<dim3(48, 8), 256, 0, stream>>>(xb, Wqt, Wkt, Wvt, KqT, KkT, qfb, kfb, kfT, VT);
    chunk_scan<<<dim3(2, NH), 256, 0, stream>>>(kfT, VT, Spb, kp);
    chunk_out_mfma<<<dim3(NC, NH), 256, 0, stream>>>(qfb, kfb, VT, Spb, kp, Yb);
    gemm_final<<<dim3(16, 16), 256, 0, stream>>>(Yb, Wot, out);
}

// Round 13
// 58.422 us; speedup vs baseline: 1.3680x; 1.1060x over previous
//
#include <hip/hip_runtime.h>
#include <hip/hip_bf16.h>

// Hedgehog linear attention, B=1, L=1024, D=1024, H=16, HD=64, FD=64.
// Round 13: R10 with prefix_scan fused into chunk_out (R11's validated
// phases 2+3, WITHOUT the flag/spin machinery — chunk_sums' kernel boundary
// is the global barrier). 5 launches.
//  1) prep: W^T bf16 (x4), x bf16, Kq/Kk^T bf16
//  2) qkv_feat: GEMM tile 128x64 + fused featmap epilogue (qf/kf/kfT/VT)
//  3) chunk_sums_mfma: Sc bf16 = V^T @ kf, ksum f32
//  4) chunk_out_pf: SP/kp prefix in LDS + Y bf16 (invz barrier kept)
//  5) gemm_final: out f32 = Y @ Wo

#define NH 16
#define NC 16

using short8 = __attribute__((ext_vector_type(8))) short;
using f32x4  = __attribute__((ext_vector_type(4))) float;
typedef const __attribute__((address_space(1))) char* gptr1;
typedef __attribute__((address_space(3))) char* lptr3;

static __device__ __forceinline__ unsigned short bf16bits(float x) {
    __hip_bfloat16 h = __float2bfloat16(x);
    return __builtin_bit_cast(unsigned short, h);
}
static __device__ __forceinline__ float b2f(unsigned short u) {
    return __builtin_bit_cast(float, (unsigned int)u << 16);
}
#define SWZ(row, cb) ((cb) ^ (((row) & 7) << 4))

template<int RS>
static __device__ __forceinline__ short8 ldfrag(const char* buf, int row, int kelem) {
    return *(const short8*)(buf + row * RS + SWZ(row, kelem * 2));
}

// ---- prep: z<4 weight transpose+convert (64x64 tiles, float4); z==4 x convert; z==5 kmat
__global__ __launch_bounds__(256) void prep(const float* __restrict__ x,
                                            const float* __restrict__ w0,
                                            const float* __restrict__ w1,
                                            const float* __restrict__ w2,
                                            const float* __restrict__ w3,
                                            const float* __restrict__ Kq,
                                            const float* __restrict__ Kk,
                                            __hip_bfloat16* __restrict__ xb,
                                            __hip_bfloat16* __restrict__ d0,
                                            __hip_bfloat16* __restrict__ d1,
                                            __hip_bfloat16* __restrict__ d2,
                                            __hip_bfloat16* __restrict__ d3,
                                            __hip_bfloat16* __restrict__ KqT,
                                            __hip_bfloat16* __restrict__ KkT) {
    const int z = blockIdx.z;
    const int tid = threadIdx.x;
    if (z < 4) {
        const float* src = (z == 0) ? w0 : (z == 1) ? w1 : (z == 2) ? w2 : w3;
        __hip_bfloat16* dst = (z == 0) ? d0 : (z == 1) ? d1 : (z == 2) ? d2 : d3;
        __shared__ float tile[64][68];
        const int bx = blockIdx.x * 64, by = blockIdx.y * 64;
#pragma unroll
        for (int j = 0; j < 4; j++) {
            const int idx = j * 256 + tid;
            const int kr = idx >> 4, c4 = idx & 15;
            float4 v = *(const float4*)&src[(size_t)(by + kr) * 1024 + bx + c4 * 4];
            *(float4*)&tile[kr][c4 * 4] = v;
        }
        __syncthreads();
        const int n = tid >> 2, k0 = (tid & 3) * 16;
        unsigned short* drow = (unsigned short*)dst + (size_t)(bx + n) * 1024 + by + k0;
#pragma unroll
        for (int q = 0; q < 4; q++) {
            ushort4 o;
            o.x = bf16bits(tile[k0 + q * 4 + 0][n]);
            o.y = bf16bits(tile[k0 + q * 4 + 1][n]);
            o.z = bf16bits(tile[k0 + q * 4 + 2][n]);
            o.w = bf16bits(tile[k0 + q * 4 + 3][n]);
            *(ushort4*)(drow + q * 4) = o;
        }
    } else if (z == 4) {
        const int blk = blockIdx.y * 16 + blockIdx.x;
#pragma unroll
        for (int j = 0; j < 4; j++) {
            const int i = blk * 4096 + j * 1024 + tid * 4;
            float4 v = *(const float4*)(x + i);
            ushort4 o;
            o.x = bf16bits(v.x); o.y = bf16bits(v.y); o.z = bf16bits(v.z); o.w = bf16bits(v.w);
            *(ushort4*)((unsigned short*)xb + i) = o;
        }
    } else {
        const int flat = blockIdx.y * 16 + blockIdx.x;
        if (flat >= 32) return;
        const int h = flat & 15;
        const float* S = (flat >> 4) ? Kk : Kq;
        __hip_bfloat16* D = (flat >> 4) ? KkT : KqT;
        __shared__ float t[64][65];
#pragma unroll
        for (int j = 0; j < 16; j++) {
            int e = tid + j * 256, r = e >> 6, c = e & 63;
            t[r][c] = S[h * 4096 + r * 64 + c];
        }
        __syncthreads();
#pragma unroll
        for (int j = 0; j < 16; j++) {
            int e = tid + j * 256, r = e >> 6, c = e & 63;
            D[h * 4096 + r * 64 + c] = __float2bfloat16(t[c][r]);
        }
    }
}

// ---- QKV GEMM + fused feature map (validated r5/r10).
__global__ __launch_bounds__(256) void qkv_feat(const __hip_bfloat16* __restrict__ A,
                                                const __hip_bfloat16* __restrict__ B0,
                                                const __hip_bfloat16* __restrict__ B1,
                                                const __hip_bfloat16* __restrict__ B2,
                                                const __hip_bfloat16* __restrict__ KqT,
                                                const __hip_bfloat16* __restrict__ KkT,
                                                __hip_bfloat16* __restrict__ qf,
                                                __hip_bfloat16* __restrict__ kf,
                                                __hip_bfloat16* __restrict__ kfT,
                                                __hip_bfloat16* __restrict__ VT) {
    __shared__ __align__(16) char smem[49152];
    const int tid = threadIdx.x;
    const int bm = blockIdx.y * 128;
    const int which = blockIdx.x >> 4;
    const int h = blockIdx.x & 15;
    const __hip_bfloat16* B = (which == 0) ? B0 : (which == 1) ? B1 : B2;
    const int bn = h * 64;
    const int wid = tid >> 6, lane = tid & 63;
    const int g = lane >> 4, r16 = lane & 15;
    const char* Ab = (const char*)A;
    const char* Bb = (const char*)B;
    f32x4 acc[2][4] = {};

#define QKV_STAGE(dstA, dstB, kbyte)                                                                   \
    do {                                                                                               \
        _Pragma("unroll") for (int it = 0; it < 4; it++) {                                             \
            const int off = it * 4096 + tid * 16;                                                      \
            const int row = off >> 7, cb = off & 127;                                                  \
            __builtin_amdgcn_global_load_lds((gptr1)(Ab + (size_t)(bm + row) * 2048 + (kbyte) + SWZ(row, cb)), \
                                             (lptr3)((dstA) + it * 4096 + wid * 1024), 16, 0, 0);      \
        }                                                                                              \
        _Pragma("unroll") for (int it = 0; it < 2; it++) {                                             \
            const int off = it * 4096 + tid * 16;                                                      \
            const int row = off >> 7, cb = off & 127;                                                  \
            __builtin_amdgcn_global_load_lds((gptr1)(Bb + (size_t)(bn + row) * 2048 + (kbyte) + SWZ(row, cb)), \
                                             (lptr3)((dstB) + it * 4096 + wid * 1024), 16, 0, 0);      \
        }                                                                                              \
    } while (0)

    QKV_STAGE(smem, smem + 32768, 0);
    for (int kt = 0; kt < 16; kt++) {
        char* Ac = smem + ((kt & 1) ? 16384 : 0);
        char* Bc = smem + 32768 + ((kt & 1) ? 8192 : 0);
        if (kt < 15) {
            char* An = smem + ((kt & 1) ? 0 : 16384);
            char* Bn = smem + 32768 + ((kt & 1) ? 0 : 8192);
            QKV_STAGE(An, Bn, (kt + 1) * 128);
            asm volatile("s_waitcnt vmcnt(6)" ::: "memory");
        } else {
            asm volatile("s_waitcnt vmcnt(0)" ::: "memory");
        }
        __builtin_amdgcn_s_barrier();
#pragma unroll
        for (int ks = 0; ks < 2; ks++) {
            short8 af[2], bfr[4];
#pragma unroll
            for (int m = 0; m < 2; m++)
                af[m] = ldfrag<128>(Ac, wid * 32 + m * 16 + r16, ks * 32 + g * 8);
#pragma unroll
            for (int n = 0; n < 4; n++)
                bfr[n] = ldfrag<128>(Bc, n * 16 + r16, ks * 32 + g * 8);
#pragma unroll
            for (int m = 0; m < 2; m++)
#pragma unroll
                for (int n = 0; n < 4; n++)
                    acc[m][n] = __builtin_amdgcn_mfma_f32_16x16x32_bf16(af[m], bfr[n], acc[m][n], 0, 0, 0);
        }
        asm volatile("s_waitcnt lgkmcnt(0)" ::: "memory");
        __builtin_amdgcn_s_barrier();
    }
#undef QKV_STAGE

    if (which == 2) {
#pragma unroll
        for (int m = 0; m < 2; m++)
#pragma unroll
            for (int n = 0; n < 4; n++) {
                const int col = bn + n * 16 + r16;
                const int row0 = bm + wid * 32 + m * 16 + g * 4;
                ushort4 v;
                v.x = bf16bits(acc[m][n][0]); v.y = bf16bits(acc[m][n][1]);
                v.z = bf16bits(acc[m][n][2]); v.w = bf16bits(acc[m][n][3]);
                *(ushort4*)((unsigned short*)VT + (size_t)col * 1024 + row0) = v;
            }
        return;
    }

    const bool kside = (which == 1);
    char* XS = smem + 32768;
#pragma unroll
    for (int m = 0; m < 2; m++)
#pragma unroll
        for (int n = 0; n < 4; n++)
#pragma unroll
            for (int i = 0; i < 4; i++) {
                const int row = wid * 32 + m * 16 + g * 4 + i;
                *(unsigned short*)(XS + row * 128 + SWZ(row, (n * 16 + r16) * 2)) = bf16bits(acc[m][n][i]);
            }
    {
        const char* KTp = (const char*)(kside ? KkT : KqT);
#pragma unroll
        for (int it = 0; it < 2; it++) {
            const int off = it * 4096 + tid * 16;
            const int row = off >> 7, cb = off & 127;
            __builtin_amdgcn_global_load_lds((gptr1)(KTp + (size_t)(h * 64 + row) * 128 + SWZ(row, cb)),
                                             (lptr3)(smem + it * 4096 + wid * 1024), 16, 0, 0);
        }
    }
    __syncthreads();

    f32x4 fr[2][4] = {};
#pragma unroll
    for (int ks = 0; ks < 2; ks++) {
        short8 af[2], bfr[4];
#pragma unroll
        for (int m = 0; m < 2; m++)
            af[m] = ldfrag<128>(XS, wid * 32 + m * 16 + r16, ks * 32 + g * 8);
#pragma unroll
        for (int n = 0; n < 4; n++)
            bfr[n] = ldfrag<128>(smem, n * 16 + r16, ks * 32 + g * 8);
#pragma unroll
        for (int m = 0; m < 2; m++)
#pragma unroll
            for (int n = 0; n < 4; n++)
                fr[m][n] = __builtin_amdgcn_mfma_f32_16x16x32_bf16(af[m], bfr[n], fr[m][n], 0, 0, 0);
    }
    if (kside) __syncthreads();

    char* ft = smem;
    __hip_bfloat16* feat = kside ? kf : qf;
#pragma unroll
    for (int m = 0; m < 2; m++)
#pragma unroll
        for (int i = 0; i < 4; i++) {
            const int row = wid * 32 + m * 16 + g * 4 + i;
            float m1 = fr[m][0][i], m2 = -fr[m][0][i];
#pragma unroll
            for (int n = 1; n < 4; n++) {
                m1 = fmaxf(m1, fr[m][n][i]);
                m2 = fmaxf(m2, -fr[m][n][i]);
            }
#pragma unroll
            for (int off = 8; off; off >>= 1) {
                m1 = fmaxf(m1, __shfl_xor(m1, off));
                m2 = fmaxf(m2, __shfl_xor(m2, off));
            }
            float e1[4], e2[4], s1 = 0.f, s2 = 0.f;
#pragma unroll
            for (int n = 0; n < 4; n++) {
                e1[n] = __expf(fr[m][n][i] - m1);  s1 += e1[n];
                e2[n] = __expf(-fr[m][n][i] - m2); s2 += e2[n];
            }
#pragma unroll
            for (int off = 8; off; off >>= 1) {
                s1 += __shfl_xor(s1, off);
                s2 += __shfl_xor(s2, off);
            }
            const float i1 = 1.f / s1, i2 = 1.f / s2;
            __hip_bfloat16* fo = feat + ((size_t)(h * 1024 + bm + row)) * 128;
#pragma unroll
            for (int n = 0; n < 4; n++) {
                const int col = n * 16 + r16;
                unsigned short v1 = bf16bits(fmaxf(e1[n] * i1, 1e-12f));
                unsigned short v2 = bf16bits(fmaxf(e2[n] * i2, 1e-12f));
                *(unsigned short*)(fo + col) = v1;
                *(unsigned short*)(fo + col + 64) = v2;
                if (kside) {
                    *(unsigned short*)(ft + col * 256 + SWZ(col, row * 2)) = v1;
                    *(unsigned short*)(ft + (col + 64) * 256 + SWZ(col + 64, row * 2)) = v2;
                }
            }
        }
    if (kside) {
        __syncthreads();
#pragma unroll
        for (int j = 0; j < 8; j++) {
            const int off = (tid + j * 256) * 16;
            const int row = off >> 8, cb = off & 255;
            short8 v = *(const short8*)(ft + row * 256 + SWZ(row, cb));
            *(short8*)((char*)kfT + ((size_t)(h * 128 + row) * 1024 + bm) * 2 + cb) = v;
        }
    }
}

// ---- Sc[h][c][d][f] bf16 = V^T @ kf ; ksum f32 (validated r5/r10)
__global__ __launch_bounds__(256) void chunk_sums_mfma(const __hip_bfloat16* __restrict__ kfT,
                                                       const __hip_bfloat16* __restrict__ VT,
                                                       __hip_bfloat16* __restrict__ Scb,
                                                       float* __restrict__ ksum) {
    const int h = blockIdx.y, c = blockIdx.x, l0 = c * 64;
    __shared__ __align__(16) char VTs[64 * 128];
    __shared__ __align__(16) char KTs[128 * 128];
    const int tid = threadIdx.x, lane = tid & 63, wid = tid >> 6;
    const int r16 = lane & 15, g = lane >> 4;
#pragma unroll
    for (int it = 0; it < 2; it++) {
        const int off = it * 4096 + tid * 16;
        const int row = off >> 7, cb = off & 127;
        __builtin_amdgcn_global_load_lds((gptr1)((const char*)VT + ((size_t)(h * 64 + row) * 1024 + l0) * 2 + SWZ(row, cb)),
                                         (lptr3)(VTs + it * 4096 + wid * 1024), 16, 0, 0);
    }
#pragma unroll
    for (int it = 0; it < 4; it++) {
        const int off = it * 4096 + tid * 16;
        const int row = off >> 7, cb = off & 127;
        __builtin_amdgcn_global_load_lds((gptr1)((const char*)kfT + ((size_t)(h * 128 + row) * 1024 + l0) * 2 + SWZ(row, cb)),
                                         (lptr3)(KTs + it * 4096 + wid * 1024), 16, 0, 0);
    }
    __syncthreads();
    f32x4 acc[8] = {};
#pragma unroll
    for (int ks = 0; ks < 2; ks++) {
        short8 a = ldfrag<128>(VTs, wid * 16 + r16, ks * 32 + g * 8);
#pragma unroll
        for (int n = 0; n < 8; n++) {
            short8 b = ldfrag<128>(KTs, n * 16 + r16, ks * 32 + g * 8);
            acc[n] = __builtin_amdgcn_mfma_f32_16x16x32_bf16(a, b, acc[n], 0, 0, 0);
        }
    }
    unsigned short* o = (unsigned short*)Scb + (size_t)(h * NC + c) * 8192;
#pragma unroll
    for (int n = 0; n < 8; n++)
#pragma unroll
        for (int i = 0; i < 4; i++)
            o[(wid * 16 + g * 4 + i) * 128 + n * 16 + r16] = bf16bits(acc[n][i]);
    if (tid < 128) {
        float s = 0.f;
#pragma unroll 8
        for (int t = 0; t < 64; t++)
            s += b2f(*(const unsigned short*)(KTs + tid * 128 + SWZ(tid, t * 2)));
        ksum[(size_t)(h * NC + c) * 128 + tid] = s;
    }
}

// ---- chunk_out_pf: SP/kp prefix built in LDS (R11 phase 2, validated) +
// chunk_out body (R10-validated, invz barrier kept). Y bf16.
__global__ __launch_bounds__(256) void chunk_out_pf(const __hip_bfloat16* __restrict__ qf,
                                                    const __hip_bfloat16* __restrict__ kf,
                                                    const __hip_bfloat16* __restrict__ VT,
                                                    const __hip_bfloat16* __restrict__ Scb,
                                                    const float* __restrict__ ksum,
                                                    __hip_bfloat16* __restrict__ Y) {
    const int h = blockIdx.y, c = blockIdx.x, l0 = c * 64;
    __shared__ __align__(16) char QF[64 * 256];
    __shared__ __align__(16) char KF[64 * 256];
    __shared__ __align__(16) char SP[64 * 256];
    __shared__ __align__(16) char VTs[64 * 128];
    __shared__ __align__(16) char AM[64 * 128];
    __shared__ float kpL[128];
    __shared__ float zi[64];
    __shared__ float invz[64];
    const int tid = threadIdx.x, lane = tid & 63, wid = tid >> 6;
    const int r16 = lane & 15, g = lane >> 4;

    // issue QF/KF/VTs staging first (latency hides under the SP prefix sum)
#pragma unroll
    for (int it = 0; it < 4; it++) {
        const int off = it * 4096 + wid * 1024 + lane * 16;
        const int row = off >> 8, cb = off & 255;
        const int sw = SWZ(row, cb);
        __builtin_amdgcn_global_load_lds((gptr1)((const char*)qf + ((size_t)(h * 1024 + l0 + row)) * 256 + sw),
                                         (lptr3)(QF + it * 4096 + wid * 1024), 16, 0, 0);
        __builtin_amdgcn_global_load_lds((gptr1)((const char*)kf + ((size_t)(h * 1024 + l0 + row)) * 256 + sw),
                                         (lptr3)(KF + it * 4096 + wid * 1024), 16, 0, 0);
    }
#pragma unroll
    for (int it = 0; it < 2; it++) {
        const int off = it * 4096 + wid * 1024 + lane * 16;
        const int row = off >> 7, cb = off & 127;
        __builtin_amdgcn_global_load_lds((gptr1)((const char*)VT + ((size_t)(h * 64 + row) * 1024 + l0) * 2 + SWZ(row, cb)),
                                         (lptr3)(VTs + it * 4096 + wid * 1024), 16, 0, 0);
    }

    // SP (bf16, swizzled LDS) = sum_{c'<c} Sc[h][c'] (f32 accum); kpL (R11 phase 2)
    {
        const int e0 = tid * 32;            // 8192 elems / 256 threads
        const int d = e0 >> 7, f0 = e0 & 127;
        float a[32];
#pragma unroll
        for (int j = 0; j < 32; j++) a[j] = 0.f;
        for (int cp = 0; cp < c; cp++) {
            const unsigned short* p = (const unsigned short*)Scb + (size_t)(h * NC + cp) * 8192 + e0;
#pragma unroll
            for (int q = 0; q < 4; q++) {
                short8 v = *(const short8*)(p + q * 8);
#pragma unroll
                for (int j = 0; j < 8; j++) a[q * 8 + j] += b2f((unsigned short)v[j]);
            }
        }
#pragma unroll
        for (int q = 0; q < 4; q++) {
            short8 w;
#pragma unroll
            for (int j = 0; j < 8; j++) w[j] = (short)bf16bits(a[q * 8 + j]);
            *(short8*)(SP + d * 256 + SWZ(d, (f0 + q * 8) * 2)) = w;
        }
        if (tid < 128) {
            float s = 0.f;
            for (int cp = 0; cp < c; cp++)
                s += ksum[(size_t)(h * NC + cp) * 128 + tid];
            kpL[tid] = s;
        }
    }
    __syncthreads();   // staging + SP + kpL complete

    f32x4 a4[4] = {};
#pragma unroll
    for (int ks = 0; ks < 4; ks++) {
        short8 a = ldfrag<256>(QF, wid * 16 + r16, ks * 32 + g * 8);
#pragma unroll
        for (int n = 0; n < 4; n++) {
            short8 bb = ldfrag<256>(KF, n * 16 + r16, ks * 32 + g * 8);
            a4[n] = __builtin_amdgcn_mfma_f32_16x16x32_bf16(a, bb, a4[n], 0, 0, 0);
        }
    }
    const int rowl = wid * 16 + g * 4;
#pragma unroll
    for (int i = 0; i < 4; i++) {
        float r = 0.f;
#pragma unroll
        for (int n = 0; n < 4; n++) {
            const int col = n * 16 + r16;
            float v = (col <= rowl + i) ? a4[n][i] : 0.f;
            a4[n][i] = v;
            r += v;
        }
#pragma unroll
        for (int off = 8; off; off >>= 1) r += __shfl_xor(r, off);
        if (r16 == 0) zi[rowl + i] = r;
#pragma unroll
        for (int n = 0; n < 4; n++)
            *(unsigned short*)(AM + (rowl + i) * 128 + SWZ(rowl + i, (n * 16 + r16) * 2)) = bf16bits(a4[n][i]);
    }
    __syncthreads();

    if (tid < 64) {
        float z = zi[tid] + 1e-12f;
#pragma unroll 8
        for (int f = 0; f < 128; f++)
            z += b2f(*(const unsigned short*)(QF + tid * 256 + SWZ(tid, f * 2))) * kpL[f];
        invz[tid] = 1.f / z;
    }

    f32x4 o4[4] = {};
#pragma unroll
    for (int ks = 0; ks < 2; ks++) {
        short8 a = ldfrag<128>(AM, wid * 16 + r16, ks * 32 + g * 8);
#pragma unroll
        for (int n = 0; n < 4; n++) {
            short8 bb = ldfrag<128>(VTs, n * 16 + r16, ks * 32 + g * 8);
            o4[n] = __builtin_amdgcn_mfma_f32_16x16x32_bf16(a, bb, o4[n], 0, 0, 0);
        }
    }
#pragma unroll
    for (int ks = 0; ks < 4; ks++) {
        short8 a = ldfrag<256>(QF, wid * 16 + r16, ks * 32 + g * 8);
#pragma unroll
        for (int n = 0; n < 4; n++) {
            short8 bb = ldfrag<256>(SP, n * 16 + r16, ks * 32 + g * 8);
            o4[n] = __builtin_amdgcn_mfma_f32_16x16x32_bf16(a, bb, o4[n], 0, 0, 0);
        }
    }
    __syncthreads();   // invz (written by wave 0) must be visible to all waves
#pragma unroll
    for (int n = 0; n < 4; n++)
#pragma unroll
        for (int i = 0; i < 4; i++) {
            const int row = rowl + i, col = n * 16 + r16;
            Y[((size_t)(l0 + row)) * 1024 + h * 64 + col] = __float2bfloat16(o4[n][i] * invz[row]);
        }
}

// ---- final GEMM: A bf16 (M x K), B^T bf16 (N x K), C f32; 64x64 tiles, 2-phase dbuf
__global__ __launch_bounds__(256) void gemm_final(const __hip_bfloat16* __restrict__ A,
                                                  const __hip_bfloat16* __restrict__ B,
                                                  float* __restrict__ C) {
    __shared__ __align__(16) char smem[32768];
    const int tid = threadIdx.x;
    const int bm = blockIdx.y * 64, bn = blockIdx.x * 64;
    const int wid = tid >> 6, lane = tid & 63;
    const int g = lane >> 4, r16 = lane & 15;
    const int wr = wid >> 1, wc = wid & 1;
    const char* Ab = (const char*)A;
    const char* Bb = (const char*)B;
    f32x4 acc[2][2] = {};

#define FIN_STAGE(dstA, dstB, kbyte)                                                                   \
    do {                                                                                               \
        _Pragma("unroll") for (int it = 0; it < 2; it++) {                                             \
            const int off = it * 4096 + tid * 16;                                                      \
            const int row = off >> 7, cb = off & 127;                                                  \
            __builtin_amdgcn_global_load_lds((gptr1)(Ab + (size_t)(bm + row) * 2048 + (kbyte) + SWZ(row, cb)), \
                                             (lptr3)((dstA) + it * 4096 + wid * 1024), 16, 0, 0);      \
            __builtin_amdgcn_global_load_lds((gptr1)(Bb + (size_t)(bn + row) * 2048 + (kbyte) + SWZ(row, cb)), \
                                             (lptr3)((dstB) + it * 4096 + wid * 1024), 16, 0, 0);      \
        }                                                                                              \
    } while (0)

    FIN_STAGE(smem, smem + 16384, 0);
    for (int kt = 0; kt < 16; kt++) {
        char* Ac = smem + ((kt & 1) ? 8192 : 0);
        char* Bc = smem + 16384 + ((kt & 1) ? 8192 : 0);
        if (kt < 15) {
            char* An = smem + ((kt & 1) ? 0 : 8192);
            char* Bn = smem + 16384 + ((kt & 1) ? 0 : 8192);
            FIN_STAGE(An, Bn, (kt + 1) * 128);
            asm volatile("s_waitcnt vmcnt(4)" ::: "memory");
        } else {
            asm volatile("s_waitcnt vmcnt(0)" ::: "memory");
        }
        __builtin_amdgcn_s_barrier();
#pragma unroll
        for (int ks = 0; ks < 2; ks++) {
            short8 af[2], bfr[2];
#pragma unroll
            for (int m = 0; m < 2; m++)
                af[m] = ldfrag<128>(Ac, wr * 32 + m * 16 + r16, ks * 32 + g * 8);
#pragma unroll
            for (int n = 0; n < 2; n++)
                bfr[n] = ldfrag<128>(Bc, wc * 32 + n * 16 + r16, ks * 32 + g * 8);
#pragma unroll
            for (int m = 0; m < 2; m++)
#pragma unroll
                for (int n = 0; n < 2; n++)
                    acc[m][n] = __builtin_amdgcn_mfma_f32_16x16x32_bf16(af[m], bfr[n], acc[m][n], 0, 0, 0);
        }
        asm volatile("s_waitcnt lgkmcnt(0)" ::: "memory");
        __builtin_amdgcn_s_barrier();
    }
#undef FIN_STAGE
#pragma unroll
    for (int m = 0; m < 2; m++)
#pragma unroll
        for (int n = 0; n < 2; n++)
#pragma unroll
            for (int i = 0; i < 4; i++) {
                const int row = bm + wr * 32 + m * 16 + g * 4 + i;
                const int col = bn + wc * 32 + n * 16 + r16;
                C[(size_t)row * 1024 + col] = acc[m][n][i];
            }
}

extern "C" void kernel_launch(void* const* d_in, const int* in_sizes, int n_in,
                              void* d_out, int out_size, void* d_ws, size_t ws_size,
                              hipStream_t stream) {
    const float* x  = (const float*)d_in[0];
    const float* Wq = (const float*)d_in[1];
    const float* Wk = (const float*)d_in[2];
    const float* Wv = (const float*)d_in[3];
    const float* Wo = (const float*)d_in[4];
    const float* Kq = (const float*)d_in[5];
    const float* Kk = (const float*)d_in[6];
    float* out = (float*)d_out;
    float* ws = (float*)d_ws;

    const size_t M1 = 1024 * 1024;
    if (ws_size < 10 * M1 * sizeof(float)) return;

    __hip_bfloat16* xb  = (__hip_bfloat16*)(ws);
    __hip_bfloat16* Wqt = (__hip_bfloat16*)(ws + M1 / 2);
    __hip_bfloat16* Wkt = (__hip_bfloat16*)(ws + 1 * M1);
    __hip_bfloat16* Wvt = (__hip_bfloat16*)(ws + 3 * M1 / 2);
    __hip_bfloat16* Wot = (__hip_bfloat16*)(ws + 2 * M1);
    __hip_bfloat16* KqT = (__hip_bfloat16*)(ws + 5 * M1 / 2);
    __hip_bfloat16* KkT = (__hip_bfloat16*)(ws + 5 * M1 / 2 + 32768);
    __hip_bfloat16* VT  = (__hip_bfloat16*)(ws + 3 * M1);
    __hip_bfloat16* qfb = (__hip_bfloat16*)(ws + 7 * M1 / 2);
    __hip_bfloat16* kfb = (__hip_bfloat16*)(ws + 9 * M1 / 2);
    __hip_bfloat16* kfT = (__hip_bfloat16*)(ws + 11 * M1 / 2);
    __hip_bfloat16* Scb = (__hip_bfloat16*)(ws + 13 * M1 / 2);
    __hip_bfloat16* Yb  = (__hip_bfloat16*)(ws + 15 * M1 / 2);
    float* ksum = ws + 9 * M1;

    prep<<<dim3(16, 16, 6), 256, 0, stream>>>(x, Wq, Wk, Wv, Wo, Kq, Kk,
                                              xb, Wqt, Wkt, Wvt, Wot, KqT, KkT);
    qkv_feat<<<dim3(48, 8), 256, 0, stream>>>(xb, Wqt, Wkt, Wvt, KqT, KkT, qfb, kfb, kfT, VT);
    chunk_sums_mfma<<<dim3(NC, NH), 256, 0, stream>>>(kfT, VT, Scb, ksum);
    chunk_out_pf<<<dim3(NC, NH), 256, 0, stream>>>(qfb, kfb, VT, Scb, ksum, Yb);
    gemm_final<<<dim3(16, 16), 256, 0, stream>>>(Yb, Wot, out);
}